// Round 1
// baseline (328.502 us; speedup 1.0000x reference)
//
#include <hip/hip_runtime.h>

// Problem constants (B=8, C=3, H=W=512, H2=W2=1024, KSIZE=5)
#define HH 512
#define WW 512
#define H2 1024
#define W2 1024
#define CPLANE (HH * WW)     // 262144 floats per input channel plane
#define OPLANE (H2 * W2)     // 1048576 floats per output channel plane

__device__ __forceinline__ float fast_rcp(float x) {
    return __builtin_amdgcn_rcpf(x);
}

// One thread computes the (even,odd) output-x pair for one (b, y2) row position.
// Both pixels share bxi = x2>>1, so the 5x5x3 input window is loaded once.
__global__ __launch_bounds__(256) void fnu_kernel(
    const float* __restrict__ inp,     // (B,3,512,512)
    const float* __restrict__ upar,    // (B,3,1024,1024)
    const float* __restrict__ skips,   // (B,3,1024,1024)
    const float* __restrict__ skipp,   // (B,1,1024,1024)
    float* __restrict__ out)           // (B,3,1024,1024)
{
    const int gid = blockIdx.x * 256 + threadIdx.x;   // 4,194,304 threads total
    const int tx = gid & 511;              // input x; output x = 2*tx, 2*tx+1
    const int y2 = (gid >> 9) & 1023;
    const int b  = gid >> 19;

    const int   ty  = y2 >> 1;
    const float dy0 = (y2 & 1) ? 0.25f : -0.25f;

    const size_t obase = ((size_t)(b * 3) * H2 + y2) * W2 + 2 * tx; // c=0 plane idx
    const size_t sbase = ((size_t)b * H2 + y2) * W2 + 2 * tx;

    // Per-pixel kernel parameters (channel-shared weights)
    const float2 p0 = *(const float2*)(upar + obase);
    const float2 p1 = *(const float2*)(upar + obase + (size_t)OPLANE);
    const float2 p2 = *(const float2*)(upar + obase + 2 * (size_t)OPLANE);

    // Coefficients with the -2 of exp(-2*dist) folded in:
    //   arg = A*dx^2 + B*dy^2 + C*dx*dy ;  w = exp(arg)
    float Av[2], Bv[2], Cv[2];
#pragma unroll
    for (int j = 0; j < 2; ++j) {
        const float u0 = j ? p0.y : p0.x;
        const float u1 = j ? p1.y : p1.x;
        const float u2 = j ? p2.y : p2.x;
        const float kx  = 4.0f * fast_rcp(1.0f + __expf(-u0));
        const float ky  = 4.0f * fast_rcp(1.0f + __expf(-u1));
        const float e   = __expf(-2.0f * u2);
        const float kxy = (1.0f - e) * fast_rcp(1.0f + e);   // tanh(u2)
        Av[j] = -2.0f * kx * kx;
        Bv[j] = -2.0f * ky * kx;          // note: ref uses ky*kx here
        Cv[j] = -4.0f * kx * ky * kxy;    // -2 * (2*kx*ky*kxy)
    }

    // Clamped x sample offsets (shared by all 5 rows and 3 channels)
    int xs[5];
#pragma unroll
    for (int i = 0; i < 5; ++i) {
        int v = tx + i - 2;
        xs[i] = v < 0 ? 0 : (v > (WW - 1) ? (WW - 1) : v);
    }

    float acc0[3] = {0.f, 0.f, 0.f};
    float acc1[3] = {0.f, 0.f, 0.f};
    float w0s = 0.f, w1s = 0.f;

    const float* ib = inp + (size_t)(b * 3) * CPLANE;

#pragma unroll
    for (int iy = 0; iy < 5; ++iy) {
        int yv = ty + iy - 2;
        const int ysrc = yv < 0 ? 0 : (yv > (HH - 1) ? (HH - 1) : yv);
        const float* row = ib + (size_t)ysrc * WW;
        const float dy  = dy0 - (float)(iy - 2);
        const float dy2 = dy * dy;
        const float bd0 = Bv[0] * dy2, bd1 = Bv[1] * dy2;
        const float cd0 = Cv[0] * dy,  cd1 = Cv[1] * dy;
#pragma unroll
        for (int ix = 0; ix < 5; ++ix) {
            const float s0 = row[xs[ix]];
            const float s1 = row[xs[ix] + CPLANE];
            const float s2 = row[xs[ix] + 2 * CPLANE];
            // dx values are compile-time constants per tap
            const float dxe = -0.25f - (float)(ix - 2);
            const float dxo =  0.25f - (float)(ix - 2);
            const float a0 = fmaf(Av[0], dxe * dxe, fmaf(cd0, dxe, bd0));
            const float a1 = fmaf(Av[1], dxo * dxo, fmaf(cd1, dxo, bd1));
            const float w0 = __expf(a0);
            const float w1 = __expf(a1);
            w0s += w0;   // w > 0, so |w| == w
            w1s += w1;
            acc0[0] = fmaf(s0, w0, acc0[0]);
            acc0[1] = fmaf(s1, w0, acc0[1]);
            acc0[2] = fmaf(s2, w0, acc0[2]);
            acc1[0] = fmaf(s0, w1, acc1[0]);
            acc1[1] = fmaf(s1, w1, acc1[1]);
            acc1[2] = fmaf(s2, w1, acc1[2]);
        }
    }

    // Epilogue: normalize + sigmoid-gated skip blend, float2 stores
    const float2 sp2 = *(const float2*)(skipp + sbase);
    const float sp0 = fast_rcp(1.0f + __expf(-sp2.x));
    const float sp1 = fast_rcp(1.0f + __expf(-sp2.y));
    const float r0 = fast_rcp(w0s + 1e-6f);
    const float r1 = fast_rcp(w1s + 1e-6f);

#pragma unroll
    for (int c = 0; c < 3; ++c) {
        const float2 sk = *(const float2*)(skips + obase + (size_t)c * OPLANE);
        const float u0 = acc0[c] * r0;
        const float u1 = acc1[c] * r1;
        float2 o;
        o.x = u0 + sp0 * (sk.x - u0);
        o.y = u1 + sp1 * (sk.y - u1);
        *(float2*)(out + obase + (size_t)c * OPLANE) = o;
    }
}

extern "C" void kernel_launch(void* const* d_in, const int* in_sizes, int n_in,
                              void* d_out, int out_size, void* d_ws, size_t ws_size,
                              hipStream_t stream) {
    const float* inp   = (const float*)d_in[0];  // input (8,3,512,512)
    const float* upar  = (const float*)d_in[1];  // upscale_params (8,3,1024,1024)
    const float* skips = (const float*)d_in[2];  // skip_signal (8,3,1024,1024)
    const float* skipp = (const float*)d_in[3];  // skip_param (8,1,1024,1024)
    float* outp = (float*)d_out;

    // 8 * 1024 * 512 = 4,194,304 threads (one per output-x pair)
    const int total = 8 * H2 * (W2 / 2);
    const int block = 256;
    const int grid  = total / block;   // 16384
    fnu_kernel<<<grid, block, 0, stream>>>(inp, upar, skips, skipp, outp);
}

// Round 2
// 288.890 us; speedup vs baseline: 1.1371x; 1.1371x over previous
//
#include <hip/hip_runtime.h>

// B=8, C=3, H=W=512, H2=W2=1024, KSIZE=5
#define HH 512
#define WW 512
#define H2 1024
#define W2 1024
#define CPLANE (HH * WW)
#define OPLANE (H2 * W2)
#define LOG2E 1.44269504088896f

__device__ __forceinline__ float rcpf_(float x)  { return __builtin_amdgcn_rcpf(x); }
__device__ __forceinline__ float exp2f_(float x) { return __builtin_amdgcn_exp2f(x); }

// One thread: 4 consecutive input-x positions => 8 output pixels on one row.
// The 4 overlapping 5-tap windows collapse into one 8-float register window
// per (row, channel), loaded as float2 + float4 + float2 (all aligned).
__global__ __launch_bounds__(256) void fnu_kernel(
    const float* __restrict__ inp,     // (B,3,512,512)
    const float* __restrict__ upar,    // (B,3,1024,1024)
    const float* __restrict__ skips,   // (B,3,1024,1024)
    const float* __restrict__ skipp,   // (B,1,1024,1024)
    float* __restrict__ out)           // (B,3,1024,1024)
{
    const int gid = blockIdx.x * 256 + threadIdx.x;   // 1,048,576 threads
    const int txg = gid & 127;
    const int tx  = txg << 2;                  // input x base (0..508, step 4)
    const int y2  = (gid >> 7) & 1023;
    const int b   = gid >> 17;

    const int   ty  = y2 >> 1;
    const float dy0 = (y2 & 1) ? 0.25f : -0.25f;    // shared by all 8 px

    const size_t obase = ((size_t)(b * 3) * H2 + y2) * W2 + 2 * tx;
    const size_t sbase = ((size_t)b * H2 + y2) * W2 + 2 * tx;

    // ---- per-pixel params (8 px), float4 loads ----
    const float4 q0a = *(const float4*)(upar + obase);
    const float4 q0b = *(const float4*)(upar + obase + 4);
    const float4 q1a = *(const float4*)(upar + obase + (size_t)OPLANE);
    const float4 q1b = *(const float4*)(upar + obase + (size_t)OPLANE + 4);
    const float4 q2a = *(const float4*)(upar + obase + 2 * (size_t)OPLANE);
    const float4 q2b = *(const float4*)(upar + obase + 2 * (size_t)OPLANE + 4);

    const float u0[8] = {q0a.x, q0a.y, q0a.z, q0a.w, q0b.x, q0b.y, q0b.z, q0b.w};
    const float u1[8] = {q1a.x, q1a.y, q1a.z, q1a.w, q1b.x, q1b.y, q1b.z, q1b.w};
    const float u2[8] = {q2a.x, q2a.y, q2a.z, q2a.w, q2b.x, q2b.y, q2b.z, q2b.w};

    // Coefficients with both the -2 of exp(-2*dist) AND log2(e) folded in:
    //   w = exp2( A*dx^2 + B*dy^2 + C*dx*dy )
    float A[8], Bc[8], Cc[8];
#pragma unroll
    for (int j = 0; j < 8; ++j) {
        const float kx  = 4.0f * rcpf_(1.0f + exp2f_(-LOG2E * u0[j]));
        const float ky  = 4.0f * rcpf_(1.0f + exp2f_(-LOG2E * u1[j]));
        const float e   = exp2f_(-2.0f * LOG2E * u2[j]);
        const float kxy = (1.0f - e) * rcpf_(1.0f + e);      // tanh(u2)
        A[j]  = -2.0f * LOG2E * kx * kx;
        Bc[j] = -2.0f * LOG2E * ky * kx;     // ref uses ky*kx
        Cc[j] = 2.0f * Bc[j] * (kx * rcpf_(ky)) * kxy;       // -4*L*kx*ky*kxy? no:
    }
    // NOTE: Cc must be -4*LOG2E*kx*ky*kxy; recompute cleanly (the line above
    // would lose precision) — done below instead.
#pragma unroll
    for (int j = 0; j < 8; ++j) {
        const float kx  = 4.0f * rcpf_(1.0f + exp2f_(-LOG2E * u0[j]));
        const float ky  = 4.0f * rcpf_(1.0f + exp2f_(-LOG2E * u1[j]));
        const float e   = exp2f_(-2.0f * LOG2E * u2[j]);
        const float kxy = (1.0f - e) * rcpf_(1.0f + e);
        A[j]  = -2.0f * LOG2E * kx * kx;
        Bc[j] = -2.0f * LOG2E * ky * kx;
        Cc[j] = -4.0f * LOG2E * kx * ky * kxy;
    }

    float acc[8][3];
    float ws[8];
#pragma unroll
    for (int j = 0; j < 8; ++j) { acc[j][0] = acc[j][1] = acc[j][2] = 0.f; ws[j] = 0.f; }

    const float* ib = inp + (size_t)(b * 3) * CPLANE;

    int ysrc[5];
#pragma unroll
    for (int iy = 0; iy < 5; ++iy) {
        int v = ty + iy - 2;
        ysrc[iy] = v < 0 ? 0 : (v > (HH - 1) ? (HH - 1) : v);
    }
    // x-window piece addresses (clamped once; fixups applied per load)
    const int axl = (tx == 0) ? 0 : tx - 2;       // left float2
    const int axr = (tx == 508) ? 510 : tx + 4;   // right float2

#pragma unroll
    for (int iy = 0; iy < 5; ++iy) {
        const float* r0 = ib + (size_t)ysrc[iy] * WW;

        float wn[3][8];   // window: wn[c][k] = row_c[tx-2+k] (clamped)
#pragma unroll
        for (int c = 0; c < 3; ++c) {
            const float* rp = r0 + (size_t)c * CPLANE;
            float2 a  = *(const float2*)(rp + axl);
            float4 m  = *(const float4*)(rp + tx);
            float2 e2 = *(const float2*)(rp + axr);
            if (tx == 0)   a.y  = a.x;    // x=-1 clamps to 0
            if (tx == 508) e2.x = e2.y;   // x=512,513 clamp to 511
            wn[c][0] = a.x;  wn[c][1] = a.y;
            wn[c][2] = m.x;  wn[c][3] = m.y; wn[c][4] = m.z; wn[c][5] = m.w;
            wn[c][6] = e2.x; wn[c][7] = e2.y;
        }

        const float dy  = dy0 - (float)(iy - 2);
        const float dy2 = dy * dy;
        float bd[8], cd[8];
#pragma unroll
        for (int j = 0; j < 8; ++j) { bd[j] = Bc[j] * dy2; cd[j] = Cc[j] * dy; }

#pragma unroll
        for (int i = 0; i < 4; ++i) {            // input-x position tx+i
            const int je = 2 * i, jo = 2 * i + 1;
#pragma unroll
            for (int ox = -2; ox <= 2; ++ox) {
                const float dxe = -0.25f - (float)ox;
                const float dxo =  0.25f - (float)ox;
                const float ae = fmaf(A[je], dxe * dxe, fmaf(cd[je], dxe, bd[je]));
                const float ao = fmaf(A[jo], dxo * dxo, fmaf(cd[jo], dxo, bd[jo]));
                const float we = exp2f_(ae);
                const float wo = exp2f_(ao);
                ws[je] += we;
                ws[jo] += wo;
                const int k = i + ox + 2;        // static after unroll
                acc[je][0] = fmaf(wn[0][k], we, acc[je][0]);
                acc[je][1] = fmaf(wn[1][k], we, acc[je][1]);
                acc[je][2] = fmaf(wn[2][k], we, acc[je][2]);
                acc[jo][0] = fmaf(wn[0][k], wo, acc[jo][0]);
                acc[jo][1] = fmaf(wn[1][k], wo, acc[jo][1]);
                acc[jo][2] = fmaf(wn[2][k], wo, acc[jo][2]);
            }
        }
    }

    // ---- epilogue: normalize + sigmoid-gated skip blend ----
    const float4 spa = *(const float4*)(skipp + sbase);
    const float4 spb = *(const float4*)(skipp + sbase + 4);
    float sp[8] = {spa.x, spa.y, spa.z, spa.w, spb.x, spb.y, spb.z, spb.w};
    float rn[8];
#pragma unroll
    for (int j = 0; j < 8; ++j) {
        sp[j] = rcpf_(1.0f + exp2f_(-LOG2E * sp[j]));
        rn[j] = rcpf_(ws[j] + 1e-6f);
    }

#pragma unroll
    for (int c = 0; c < 3; ++c) {
        const float4 ska = *(const float4*)(skips + obase + (size_t)c * OPLANE);
        const float4 skb = *(const float4*)(skips + obase + (size_t)c * OPLANE + 4);
        const float skv[8] = {ska.x, ska.y, ska.z, ska.w, skb.x, skb.y, skb.z, skb.w};
        float ov[8];
#pragma unroll
        for (int j = 0; j < 8; ++j) {
            const float u = acc[j][c] * rn[j];
            ov[j] = u + sp[j] * (skv[j] - u);
        }
        float4 oa = {ov[0], ov[1], ov[2], ov[3]};
        float4 ob = {ov[4], ov[5], ov[6], ov[7]};
        *(float4*)(out + obase + (size_t)c * OPLANE)     = oa;
        *(float4*)(out + obase + (size_t)c * OPLANE + 4) = ob;
    }
}

extern "C" void kernel_launch(void* const* d_in, const int* in_sizes, int n_in,
                              void* d_out, int out_size, void* d_ws, size_t ws_size,
                              hipStream_t stream) {
    const float* inp   = (const float*)d_in[0];
    const float* upar  = (const float*)d_in[1];
    const float* skips = (const float*)d_in[2];
    const float* skipp = (const float*)d_in[3];
    float* outp = (float*)d_out;

    const int total = 8 * H2 * (WW / 4);   // 1,048,576 threads
    const int block = 256;
    const int grid  = total / block;       // 4096
    fnu_kernel<<<grid, block, 0, stream>>>(inp, upar, skips, skipp, outp);
}